// Round 18
// baseline (169.926 us; speedup 1.0000x reference)
//
#include <hip/hip_runtime.h>
#include <cstdint>

#define Bn 4
#define DIMn 256
#define Ln 4096
#define C2n 512
#define CBn 256
#define HDn 32
#define Mtot (Bn * Ln)

using bf16x8 = __attribute__((ext_vector_type(8))) short;
using us8 = __attribute__((ext_vector_type(8))) ushort;
using f32x4 = __attribute__((ext_vector_type(4))) float;

static constexpr float kScale = 0.17677669529663687f;  // 32^-0.5
static constexpr float kEps = 1e-5f;
static constexpr float kExpC = 0.17677669529663687f * 1.4426950408889634f;

__device__ __forceinline__ ushort f2bf(float f) {
  union {
    float f;
    unsigned u;
  } v;
  v.f = f;
  unsigned r = v.u + 0x7FFFu + ((v.u >> 16) & 1u);
  return (ushort)(r >> 16);
}

__device__ __forceinline__ float bf2f(ushort u) {
  union {
    unsigned u;
    float f;
  } v;
  v.u = (unsigned)u << 16;
  return v.f;
}

// packed 2xf32 -> 2xbf16 (RNE), src0 -> low half [T12 primitive]
__device__ __forceinline__ unsigned cvtpk(float lo, float hi) {
  unsigned r;
  asm("v_cvt_pk_bf16_f32 %0, %1, %2" : "=v"(r) : "v"(lo), "v"(hi));
  return r;
}

__device__ __forceinline__ void gload16(const void* g, void* l) {
  __builtin_amdgcn_global_load_lds(
      (const __attribute__((address_space(1))) unsigned*)g,
      (__attribute__((address_space(3))) unsigned*)l, 16, 0, 0);
}

// ---------------------------------------------------------------------------
// bf16 MFMA GEMM, m97 structure (HW-verified R4/R5): 128x128 tile, BK=64,
// 4 waves 2x2 of 64x64, 16x16x32 MFMA, linear LDS, gload16 staging.
// XCD-aware bijective block remap (T1, verified R16).
// R18: G_QKV epilogue now LDS-bounces the output tile (end-of-kernel double
// barrier, cvt_x-style) so q/k/v permuted stores are 64B-contiguous chunks
// (4x ushort8 per 32-channel group) and vrow rows are 128B-contiguous --
// replaces 2B scalar stores (~50% sector efficiency) on the 67 MB writer.
// As/Bs padded to stride-72 rows for the bounce (16B-aligned, 4-way banks).
// ---------------------------------------------------------------------------
enum { G_EMBED = 0, G_QKV = 1, G_PROJ = 2 };

template <int MODE, int ND, int KD, int LDB>
__global__ __launch_bounds__(256) void gemm_bf(
    const ushort* __restrict__ A, const ushort* __restrict__ Bt,
    const ushort* __restrict__ resid, const float* __restrict__ bias,
    ushort* __restrict__ aux, ushort* __restrict__ kp,
    ushort* __restrict__ vp, ushort* __restrict__ vrow) {
  constexpr int NT = ND / 128;
  __shared__ ushort As[128 * 72];
  __shared__ ushort Bs[128 * 72];

  const int tid = threadIdx.x;
  const int wid = tid >> 6;
  const int lane = tid & 63;
  // XCD remap: blk -> widx so same-A-panel blocks are consecutive per XCD
  const int per = (int)gridDim.x >> 3;
  const int widx = (blockIdx.x & 7) * per + (blockIdx.x >> 3);
  const int m0 = (widx / NT) * 128;
  const int n0 = (widx % NT) * 128;

  const int gs = (wid < 2) ? KD : LDB;
  const ushort* gsrc = (wid < 2)
                           ? A + (size_t)(m0 + (wid & 1) * 64) * KD
                           : Bt + (size_t)(n0 + (wid & 1) * 64) * LDB;
  ushort* lbase = (wid < 2 ? As : Bs) + (wid & 1) * (64 * 64);
  const int r8 = lane >> 3;
  const int c8 = lane & 7;

  f32x4 acc[4][4];
#pragma unroll
  for (int i = 0; i < 4; ++i)
#pragma unroll
    for (int j = 0; j < 4; ++j) acc[i][j] = (f32x4){0.f, 0.f, 0.f, 0.f};

  const int wm = (wid & 1) * 64;
  const int wn = (wid >> 1) * 64;
  const int lr = lane & 15;
  const int kq = lane >> 4;

  for (int k0 = 0; k0 < KD; k0 += 64) {
    __syncthreads();
#pragma unroll
    for (int i = 0; i < 8; ++i) {
      const ushort* g = gsrc + (size_t)(i * 8 + r8) * gs + (k0 + c8 * 8);
      gload16(g, lbase + i * 512);
    }
    __syncthreads();
#pragma unroll
    for (int kk = 0; kk < 2; ++kk) {
      bf16x8 af[4], bfr[4];
#pragma unroll
      for (int i = 0; i < 4; ++i)
        af[i] = *(const bf16x8*)(As + (wm + i * 16 + lr) * 64 +
                                 (kk * 4 + kq) * 8);
#pragma unroll
      for (int j = 0; j < 4; ++j)
        bfr[j] = *(const bf16x8*)(Bs + (wn + j * 16 + lr) * 64 +
                                  (kk * 4 + kq) * 8);
#pragma unroll
      for (int i = 0; i < 4; ++i)
#pragma unroll
        for (int j = 0; j < 4; ++j)
          acc[i][j] = __builtin_amdgcn_mfma_f32_16x16x32_bf16(
              af[i], bfr[j], acc[i][j], 0, 0, 0);
    }
  }

  if constexpr (MODE == G_QKV) {
    // ---- LDS-bounce epilogue: stage bf16 tile (q pre-scaled), wide store
    const bool isQ = (n0 < 512);
    ushort* st = (wn == 0) ? As : Bs;  // half-tile by wave column
    __syncthreads();  // all waves done reading As/Bs in the main loop
#pragma unroll
    for (int i = 0; i < 4; ++i)
#pragma unroll
      for (int j = 0; j < 4; ++j)
#pragma unroll
        for (int t = 0; t < 4; ++t) {
          const int row = wm + i * 16 + kq * 4 + t;
          const int colh = j * 16 + lr;
          float v = acc[i][j][t];
          if (isQ) v *= kExpC;
          st[row * 72 + colh] = f2bf(v);
        }
    __syncthreads();
    {
      const int row = tid >> 1;
      const int hf = tid & 1;
      const ushort* src = (hf ? Bs : As) + row * 72;
      const int mr = m0 + row;
      const int bb = mr >> 12;
      const int l = mr & 4095;
#pragma unroll
      for (int g2 = 0; g2 < 2; ++g2) {
        const int nc0 = n0 + hf * 64 + g2 * 32;  // group base channel
        const int sect = nc0 >> 9;               // 0=q 1=k 2=v (uniform)
        const int c0 = nc0 & 511;
        const int br = c0 >> 8;
        const int hd = (c0 >> 5) & 7;
        const int win = br ? (l >> 9) : ((l >> 3) & 7);
        const int pp = br ? (l & 511) : (((l >> 6) << 3) | (l & 7));
        const size_t off =
            (((((size_t)br * 4 + bb) * 8 + win) * 8 + hd) * 512 + pp) * 32;
        ushort* dst = (sect == 0) ? aux : (sect == 1 ? kp : vp);
#pragma unroll
        for (int cc = 0; cc < 4; ++cc) {
          const us8 v8 = *(const us8*)(src + g2 * 32 + cc * 8);
          *(us8*)(dst + off + cc * 8) = v8;
          if (sect == 2) *(us8*)(vrow + (size_t)mr * 512 + c0 + cc * 8) = v8;
        }
      }
    }
    return;
  }

#pragma unroll
  for (int i = 0; i < 4; ++i) {
#pragma unroll
    for (int j = 0; j < 4; ++j) {
#pragma unroll
      for (int t = 0; t < 4; ++t) {
        const int mr = m0 + wm + i * 16 + kq * 4 + t;
        const int nc = n0 + wn + j * 16 + lr;
        const float val = acc[i][j][t];
        if constexpr (MODE == G_EMBED) {
          aux[(size_t)mr * 512 + nc] = f2bf(val);
        } else {  // G_PROJ
          const float v2 =
              val + bf2f(resid[(size_t)mr * 512 + nc]) + bias[nc];
          aux[(size_t)mr * 512 + nc] = f2bf(v2);
        }
      }
    }
  }
}

// ---------------------------------------------------------------------------
// Merged OUT+VOUT GEMM (one dispatch, grid 512) with the same XCD remap:
// blocks' widx [0,256) -> out = w_out^T @ xo^T, [256,512) -> vout (v).
// ---------------------------------------------------------------------------
__global__ __launch_bounds__(256) void gemm_out2(
    const ushort* __restrict__ A, const ushort* __restrict__ Bt0,
    const ushort* __restrict__ Bt1, float* __restrict__ C) {
  constexpr int KD = 512;
  constexpr int NT = Mtot / 128;  // 128
  __shared__ ushort As[128 * 64];
  __shared__ ushort Bs[128 * 64];

  const int widx = (blockIdx.x & 7) * 64 + (blockIdx.x >> 3);
  const int sel = widx >> 8;
  const int bid = widx & 255;
  const ushort* Bt = sel ? Bt1 : Bt0;
  const size_t outBase = sel ? (size_t)Bn * DIMn * Ln : 0;

  const int tid = threadIdx.x;
  const int wid = tid >> 6;
  const int lane = tid & 63;
  const int m0 = (bid / NT) * 128;
  const int n0 = (bid % NT) * 128;

  const ushort* gsrc = (wid < 2)
                           ? A + (size_t)(m0 + (wid & 1) * 64) * KD
                           : Bt + (size_t)(n0 + (wid & 1) * 64) * KD;
  ushort* lbase = (wid < 2 ? As : Bs) + (wid & 1) * (64 * 64);
  const int r8 = lane >> 3;
  const int c8 = lane & 7;

  f32x4 acc[4][4];
#pragma unroll
  for (int i = 0; i < 4; ++i)
#pragma unroll
    for (int j = 0; j < 4; ++j) acc[i][j] = (f32x4){0.f, 0.f, 0.f, 0.f};

  const int wm = (wid & 1) * 64;
  const int wn = (wid >> 1) * 64;
  const int lr = lane & 15;
  const int kq = lane >> 4;

  for (int k0 = 0; k0 < KD; k0 += 64) {
    __syncthreads();
#pragma unroll
    for (int i = 0; i < 8; ++i) {
      const ushort* g = gsrc + (size_t)(i * 8 + r8) * KD + (k0 + c8 * 8);
      gload16(g, lbase + i * 512);
    }
    __syncthreads();
#pragma unroll
    for (int kk = 0; kk < 2; ++kk) {
      bf16x8 af[4], bfr[4];
#pragma unroll
      for (int i = 0; i < 4; ++i)
        af[i] = *(const bf16x8*)(As + (wm + i * 16 + lr) * 64 +
                                 (kk * 4 + kq) * 8);
#pragma unroll
      for (int j = 0; j < 4; ++j)
        bfr[j] = *(const bf16x8*)(Bs + (wn + j * 16 + lr) * 64 +
                                  (kk * 4 + kq) * 8);
#pragma unroll
      for (int i = 0; i < 4; ++i)
#pragma unroll
        for (int j = 0; j < 4; ++j)
          acc[i][j] = __builtin_amdgcn_mfma_f32_16x16x32_bf16(
              af[i], bfr[j], acc[i][j], 0, 0, 0);
    }
  }

#pragma unroll
  for (int i = 0; i < 4; ++i)
#pragma unroll
    for (int j = 0; j < 4; ++j)
#pragma unroll
      for (int t = 0; t < 4; ++t) {
        const int mr = m0 + wm + i * 16 + kq * 4 + t;  // channel
        const int nc = n0 + wn + j * 16 + lr;          // token
        C[outBase + ((size_t)(nc >> 12)) * ((size_t)DIMn * Ln) +
          (size_t)mr * Ln + (nc & 4095)] = acc[i][j][t];
      }
}

// ---------------------------------------------------------------------------
// Merged conversions, one dispatch (grid 1344):
//  blocks [0,320): weight transposes (f32 [K][N] -> bf16 [N][K], 64x64 tiles)
//  blocks [320,1344): x [B][256][4096] f32 -> xe [B*4096][256] bf16
// ---------------------------------------------------------------------------
__global__ __launch_bounds__(256) void cvt_all(
    const float* __restrict__ w_embed, const float* __restrict__ w_qkv,
    const float* __restrict__ w_proj, const float* __restrict__ w_out,
    const float* __restrict__ x, ushort* __restrict__ we_t,
    ushort* __restrict__ wq_t, ushort* __restrict__ wp_t,
    ushort* __restrict__ wo_t, ushort* __restrict__ xe) {
  __shared__ ushort tile[64][65];
  const int blk0 = blockIdx.x;
  if (blk0 < 320) {
    const int blk = blk0;
    const float* in;
    ushort* out;
    int K, N, ti;
    if (blk < 32) {
      in = w_embed; out = we_t; K = 256; N = 512; ti = blk;
    } else if (blk < 224) {
      in = w_qkv; out = wq_t; K = 512; N = 1536; ti = blk - 32;
    } else if (blk < 288) {
      in = w_proj; out = wp_t; K = 512; N = 512; ti = blk - 224;
    } else {
      in = w_out; out = wo_t; K = 512; N = 256; ti = blk - 288;
    }
    const int ntN = N >> 6;
    const int k0 = (ti / ntN) << 6;
    const int n0 = (ti % ntN) << 6;
    const int c = threadIdx.x & 63;
    const int g = threadIdx.x >> 6;
#pragma unroll
    for (int it = 0; it < 16; ++it) {
      const int r = it * 4 + g;
      tile[r][c] = f2bf(in[(size_t)(k0 + r) * N + n0 + c]);
    }
    __syncthreads();
#pragma unroll
    for (int it = 0; it < 16; ++it) {
      const int nn = it * 4 + g;
      out[(size_t)(n0 + nn) * K + k0 + c] = tile[c][nn];
    }
  } else {
    const int blk = blk0 - 320;
    const int lt = blk & 63;
    const int ct = (blk >> 6) & 3;
    const int b = blk >> 8;
    const int l0 = lt * 64, c0 = ct * 64;
    const int t = threadIdx.x;
    const int lanel = t & 63;
    const int grp = t >> 6;
#pragma unroll
    for (int it = 0; it < 16; ++it) {
      const int c = grp * 16 + it;
      tile[c][lanel] = f2bf(
          x[(size_t)b * (DIMn * Ln) + (size_t)(c0 + c) * Ln + l0 + lanel]);
    }
    __syncthreads();
#pragma unroll
    for (int it = 0; it < 16; ++it) {
      const int l = grp * 16 + it;
      xe[((size_t)b * Ln + l0 + l) * 256 + c0 + lanel] = tile[lanel][l];
    }
  }
}

__global__ __launch_bounds__(128) void ln_fuse(const ushort* __restrict__ x2,
                                               const float* __restrict__ g1,
                                               const float* __restrict__ b1,
                                               ushort* __restrict__ xln) {
  const int row = blockIdx.x;
  const int t = threadIdx.x;
  const ushort4 u4 = *(const ushort4*)&x2[(size_t)row * 512 + t * 4];
  float v[4] = {bf2f(u4.x), bf2f(u4.y), bf2f(u4.z), bf2f(u4.w)};
  float s = v[0] + v[1] + v[2] + v[3];
  float s2 = v[0] * v[0] + v[1] * v[1] + v[2] * v[2] + v[3] * v[3];
#pragma unroll
  for (int off = 32; off > 0; off >>= 1) {
    s += __shfl_down(s, off);
    s2 += __shfl_down(s2, off);
  }
  __shared__ float red[4];
  if ((t & 63) == 0) {
    red[t >> 6] = s;
    red[2 + (t >> 6)] = s2;
  }
  __syncthreads();
  const float S = red[0] + red[1];
  const float S2 = red[2] + red[3];
  const float mu = S * (1.f / 512.f);
  const float rs = rsqrtf(S2 * (1.f / 512.f) - mu * mu + kEps);
  const float4 g = *(const float4*)&g1[t * 4];
  const float4 bb = *(const float4*)&b1[t * 4];
  ushort4 o;
  o.x = f2bf((v[0] - mu) * rs * g.x + bb.x);
  o.y = f2bf((v[1] - mu) * rs * g.y + bb.y);
  o.z = f2bf((v[2] - mu) * rs * g.z + bb.z);
  o.w = f2bf((v[3] - mu) * rs * g.w + bb.w);
  *(ushort4*)&xln[(size_t)row * 512 + t * 4] = o;
}

// ---------------------------------------------------------------------------
// MFMA attention + LePE — R12-EXACT (HW-proven; sync schedule FROZEN:
// R13/R14/R17 kt-loop edits all NaN'd). Permuted q/k/v, XCD-paired
// qh-halves, 2 barriers/iter, in-loop K staging, lane-local softmax.
// ---------------------------------------------------------------------------
__global__ __launch_bounds__(256, 4) void attn_m(
    const ushort* __restrict__ qp, const ushort* __restrict__ kp,
    const ushort* __restrict__ vp, ushort* __restrict__ obf,
    const float* __restrict__ cw0, const float* __restrict__ cb0,
    const float* __restrict__ cw1, const float* __restrict__ cb1) {
  __shared__ ushort VtS[32 * 520];  // Vt[d][token]
  __shared__ ushort KsS[32 * 40];   // permuted key tiles
  __shared__ float denS[4 * 64];
  __shared__ float cwS[288];
  __shared__ float cbS[32];

  // XCD pairing: qh-pair (work 2k,2k+1) <-> blockIdx 8 apart -> same XCD
  const int work = ((blockIdx.x & 7) << 7) | (blockIdx.x >> 3);
  const int branch = work >> 9;
  const int b = (work >> 7) & 3;
  const int win = (work >> 4) & 7;
  const int head = (work >> 1) & 7;
  const int qh = work & 1;
  const int tid = threadIdx.x;
  const int w = tid >> 6;
  const int lane = tid & 63;
  const int lr = lane & 15;
  const int kq = lane >> 4;
  const int qcol = branch * CBn + head * HDn;

  const float* cw = branch ? cw1 : cw0;
  const float* cb = branch ? cb1 : cb0;
  for (int i = tid; i < 288; i += 256) cwS[i] = cw[head * 288 + i];
  if (tid < 32) cbS[tid] = cb[head * 32 + tid];

  auto tok2l = [&](int p) -> int {
    return branch == 0 ? ((p >> 3) * 64 + win * 8 + (p & 7)) : (win * 512 + p);
  };
  // base of this (branch,b,win,head) slab in the permuted layout
  const size_t base =
      (((((size_t)branch * 4 + b) * 8 + win) * 8 + head) * 512) * 32;

  // ---- stage Vt[d][p]: 64B/thread, fully sequential ----
#pragma unroll
  for (int rr = 0; rr < 2; ++rr) {
    const int j = tid + rr * 256;
    const ushort* vrow = vp + base + (size_t)j * 32;
#pragma unroll
    for (int g = 0; g < 4; ++g) {
      const bf16x8 u = *(const bf16x8*)(vrow + g * 8);
#pragma unroll
      for (int e = 0; e < 8; ++e)
        VtS[(g * 8 + e) * 520 + j] = (ushort)u[e];
    }
  }

  // ---- preload Q B-frags (pre-scaled by kExpC in QKV epilogue) ----
  bf16x8 qf[4];
#pragma unroll
  for (int qt = 0; qt < 4; ++qt) {
    const int p = qh * 256 + w * 64 + qt * 16 + lr;
    qf[qt] = *(const bf16x8*)(qp + base + (size_t)p * 32 + kq * 8);
  }

  f32x4 acc[4][2];
#pragma unroll
  for (int qt = 0; qt < 4; ++qt) {
    acc[qt][0] = (f32x4){0.f, 0.f, 0.f, 0.f};
    acc[qt][1] = (f32x4){0.f, 0.f, 0.f, 0.f};
  }
  float den[4] = {};
  const f32x4 zero4 = (f32x4){0.f, 0.f, 0.f, 0.f};

  for (int kt = 0; kt < 16; ++kt) {
    const int k0 = kt * 32;
    __syncthreads();
    // stage K tile, PERMUTED rows: key j -> row ((j>>2)&1)*16+(j>>3)*4+(j&3)
    {
      const int j = tid >> 3;
      const int d0 = (tid & 7) * 4;
      const int row = ((j >> 2) & 1) * 16 + (j >> 3) * 4 + (j & 3);
      const ushort4 k4 =
          *(const ushort4*)(kp + base + (size_t)(k0 + j) * 32 + d0);
      *(ushort4*)&KsS[row * 40 + d0] = k4;
    }
    __syncthreads();

    const bf16x8 kf0 = *(const bf16x8*)&KsS[lr * 40 + kq * 8];
    const bf16x8 kf1 = *(const bf16x8*)&KsS[(16 + lr) * 40 + kq * 8];
    const bf16x8 vf0 = *(const bf16x8*)&VtS[lr * 520 + k0 + kq * 8];
    const bf16x8 vf1 = *(const bf16x8*)&VtS[(16 + lr) * 520 + k0 + kq * 8];

#pragma unroll
    for (int qt = 0; qt < 4; ++qt) {
      // swapped: S[q=lr][key] lands in-lane
      const f32x4 s0 =
          __builtin_amdgcn_mfma_f32_16x16x32_bf16(kf0, qf[qt], zero4, 0, 0, 0);
      const f32x4 s1 =
          __builtin_amdgcn_mfma_f32_16x16x32_bf16(kf1, qf[qt], zero4, 0, 0, 0);
      float e0[4], e1[4];
#pragma unroll
      for (int t = 0; t < 4; ++t) {
        e0[t] = __builtin_amdgcn_exp2f(s0[t]);
        e1[t] = __builtin_amdgcn_exp2f(s1[t]);
      }
      den[qt] += (e0[0] + e0[1] + e0[2] + e0[3]) +
                 (e1[0] + e1[1] + e1[2] + e1[3]);
      union {
        unsigned u[4];
        bf16x8 v;
      } pa;
      pa.u[0] = cvtpk(e0[0], e0[1]);
      pa.u[1] = cvtpk(e0[2], e0[3]);
      pa.u[2] = cvtpk(e1[0], e1[1]);
      pa.u[3] = cvtpk(e1[2], e1[3]);
      acc[qt][0] = __builtin_amdgcn_mfma_f32_16x16x32_bf16(pa.v, vf0,
                                                           acc[qt][0], 0, 0, 0);
      acc[qt][1] = __builtin_amdgcn_mfma_f32_16x16x32_bf16(pa.v, vf1,
                                                           acc[qt][1], 0, 0, 0);
    }
  }

  // ---- den: reduce across kq lanes, bounce through per-wave LDS ----
#pragma unroll
  for (int qt = 0; qt < 4; ++qt) {
    float d = den[qt];
    d += __shfl_xor(d, 16);
    d += __shfl_xor(d, 32);
    if (lane < 16) denS[w * 64 + qt * 16 + lr] = d;
  }
  __syncthreads();

  // ---- epilogue: O = PV/den + LePE(Vt), write bf16 ----
  const int Hs = branch ? 8 : 64;
  const int Ws = branch ? 64 : 8;
#pragma unroll
  for (int qt = 0; qt < 4; ++qt) {
#pragma unroll
    for (int t = 0; t < 4; ++t) {
      const int p = qh * 256 + w * 64 + qt * 16 + kq * 4 + t;
      const int l = tok2l(p);
      const int hl = branch ? (p >> 6) : (p >> 3);
      const int wl = branch ? (p & 63) : (p & 7);
      const float inv = 1.f / denS[w * 64 + qt * 16 + kq * 4 + t];
      ushort* orow = obf + ((size_t)b * Ln + l) * 512 + qcol;
#pragma unroll
      for (int dt = 0; dt < 2; ++dt) {
        const int d = dt * 16 + lr;
        float le = cbS[d];
#pragma unroll
        for (int dh = -1; dh <= 1; ++dh) {
          const int hh = hl + dh;
          if (hh < 0 || hh >= Hs) continue;
#pragma unroll
          for (int dw = -1; dw <= 1; ++dw) {
            const int ww = wl + dw;
            if (ww < 0 || ww >= Ws) continue;
            const int pp = hh * Ws + ww;
            le = fmaf(bf2f(VtS[d * 520 + pp]),
                      cwS[d * 9 + (dh + 1) * 3 + (dw + 1)], le);
          }
        }
        orow[d] = f2bf(fmaf(acc[qt][dt][t], inv, le));
      }
    }
  }
}

// ---------------------------------------------------------------------------
extern "C" void kernel_launch(void* const* d_in, const int* in_sizes, int n_in,
                              void* d_out, int out_size, void* d_ws,
                              size_t ws_size, hipStream_t stream) {
  const float* x = (const float*)d_in[0];
  const float* w_embed = (const float*)d_in[1];
  const float* g1 = (const float*)d_in[2];
  const float* b1 = (const float*)d_in[3];
  const float* w_qkv = (const float*)d_in[4];
  const float* cw0 = (const float*)d_in[5];
  const float* cb0 = (const float*)d_in[6];
  const float* cw1 = (const float*)d_in[7];
  const float* cb1 = (const float*)d_in[8];
  const float* w_proj = (const float*)d_in[9];
  const float* b_proj = (const float*)d_in[10];
  const float* w_out = (const float*)d_in[11];
  float* out = (float*)d_out;

  // carve: x2 16.8 | qp 16.8 | kp 16.8 | vp 16.8 | vrow 16.8 | obf 16.8 |
  //        xln/xobf 16.8 | xe 8.4 | weights 2.6  => ~129 MB (< proven 134)
  char* p = (char*)d_ws;
  ushort* x2bf = (ushort*)p;
  p += (size_t)Mtot * 512 * 2;
  ushort* qp = (ushort*)p;
  p += (size_t)Mtot * 512 * 2;
  ushort* kp = (ushort*)p;
  p += (size_t)Mtot * 512 * 2;
  ushort* vp = (ushort*)p;
  p += (size_t)Mtot * 512 * 2;
  ushort* vrow = (ushort*)p;
  p += (size_t)Mtot * 512 * 2;
  ushort* obf = (ushort*)p;
  p += (size_t)Mtot * 512 * 2;
  ushort* xln = (ushort*)p;  // later reused as xobf
  ushort* xobf = (ushort*)p;
  p += (size_t)Mtot * 512 * 2;
  ushort* xe = (ushort*)p;
  p += (size_t)Mtot * 256 * 2;
  ushort* we_t = (ushort*)p;
  p += (size_t)512 * 256 * 2;
  ushort* wq_t = (ushort*)p;
  p += (size_t)1536 * 512 * 2;
  ushort* wp_t = (ushort*)p;
  p += (size_t)512 * 512 * 2;
  ushort* wo_t = (ushort*)p;

  // merged conversions: 320 weight-tiles + 1024 x-tiles in one dispatch
  cvt_all<<<dim3(1344), 256, 0, stream>>>(w_embed, w_qkv, w_proj, w_out, x,
                                          we_t, wq_t, wp_t, wo_t, xe);

  gemm_bf<G_EMBED, 512, 256, 256><<<dim3(128 * 4), 256, 0, stream>>>(
      xe, we_t, nullptr, nullptr, x2bf, nullptr, nullptr, nullptr);
  ln_fuse<<<dim3(Mtot), 128, 0, stream>>>(x2bf, g1, b1, xln);
  gemm_bf<G_QKV, 1536, 512, 512><<<dim3(128 * 12), 256, 0, stream>>>(
      xln, wq_t, nullptr, nullptr, qp, kp, vp, vrow);
  attn_m<<<dim3(1024), 256, 0, stream>>>(qp, kp, vp, obf, cw0, cb0, cw1, cb1);
  gemm_bf<G_PROJ, 512, 512, 512><<<dim3(128 * 4), 256, 0, stream>>>(
      obf, wp_t, x2bf, b_proj, xobf, nullptr, nullptr, nullptr);
  // merged out+vout with XCD remap inside
  gemm_out2<<<dim3(512), 256, 0, stream>>>(wo_t, xobf, vrow, out);
}

// Round 19
// 161.634 us; speedup vs baseline: 1.0513x; 1.0513x over previous
//
#include <hip/hip_runtime.h>
#include <cstdint>

#define Bn 4
#define DIMn 256
#define Ln 4096
#define C2n 512
#define CBn 256
#define HDn 32
#define Mtot (Bn * Ln)

using bf16x8 = __attribute__((ext_vector_type(8))) short;
using f32x4 = __attribute__((ext_vector_type(4))) float;

static constexpr float kScale = 0.17677669529663687f;  // 32^-0.5
static constexpr float kEps = 1e-5f;
static constexpr float kExpC = 0.17677669529663687f * 1.4426950408889634f;

__device__ __forceinline__ ushort f2bf(float f) {
  union {
    float f;
    unsigned u;
  } v;
  v.f = f;
  unsigned r = v.u + 0x7FFFu + ((v.u >> 16) & 1u);
  return (ushort)(r >> 16);
}

__device__ __forceinline__ float bf2f(ushort u) {
  union {
    unsigned u;
    float f;
  } v;
  v.u = (unsigned)u << 16;
  return v.f;
}

// packed 2xf32 -> 2xbf16 (RNE), src0 -> low half [T12 primitive]
__device__ __forceinline__ unsigned cvtpk(float lo, float hi) {
  unsigned r;
  asm("v_cvt_pk_bf16_f32 %0, %1, %2" : "=v"(r) : "v"(lo), "v"(hi));
  return r;
}

__device__ __forceinline__ void gload16(const void* g, void* l) {
  __builtin_amdgcn_global_load_lds(
      (const __attribute__((address_space(1))) unsigned*)g,
      (__attribute__((address_space(3))) unsigned*)l, 16, 0, 0);
}

// ---------------------------------------------------------------------------
// bf16 MFMA GEMM, m97 structure (HW-verified R4/R5): 128x128 tile, BK=64,
// 4 waves 2x2 of 64x64, 16x16x32 MFMA, linear LDS, gload16 staging.
// XCD-aware bijective block remap (T1, verified R16): each XCD gets nwg/8
// CONSECUTIVE work items so all N-blocks sharing an A-panel run on one XCD.
// G_QKV epilogue scatters q/k/v into the attention-permuted layout and
// echoes v row-major; q pre-scaled by kExpC. (Scalar stores: R18's LDS-bounce
// wide-store variant measured SLOWER — permuted 2B stores already coalesce.)
// ---------------------------------------------------------------------------
enum { G_EMBED = 0, G_QKV = 1, G_PROJ = 2 };

template <int MODE, int ND, int KD, int LDB>
__global__ __launch_bounds__(256) void gemm_bf(
    const ushort* __restrict__ A, const ushort* __restrict__ Bt,
    const ushort* __restrict__ resid, const float* __restrict__ bias,
    ushort* __restrict__ aux, ushort* __restrict__ kp,
    ushort* __restrict__ vp, ushort* __restrict__ vrow) {
  constexpr int NT = ND / 128;
  __shared__ ushort As[128 * 64];
  __shared__ ushort Bs[128 * 64];

  const int tid = threadIdx.x;
  const int wid = tid >> 6;
  const int lane = tid & 63;
  // XCD remap: blk -> widx so same-A-panel blocks are consecutive per XCD
  const int per = (int)gridDim.x >> 3;
  const int widx = (blockIdx.x & 7) * per + (blockIdx.x >> 3);
  const int m0 = (widx / NT) * 128;
  const int n0 = (widx % NT) * 128;

  const int gs = (wid < 2) ? KD : LDB;
  const ushort* gsrc = (wid < 2)
                           ? A + (size_t)(m0 + (wid & 1) * 64) * KD
                           : Bt + (size_t)(n0 + (wid & 1) * 64) * LDB;
  ushort* lbase = (wid < 2 ? As : Bs) + (wid & 1) * (64 * 64);
  const int r8 = lane >> 3;
  const int c8 = lane & 7;

  f32x4 acc[4][4];
#pragma unroll
  for (int i = 0; i < 4; ++i)
#pragma unroll
    for (int j = 0; j < 4; ++j) acc[i][j] = (f32x4){0.f, 0.f, 0.f, 0.f};

  const int wm = (wid & 1) * 64;
  const int wn = (wid >> 1) * 64;
  const int lr = lane & 15;
  const int kq = lane >> 4;

  for (int k0 = 0; k0 < KD; k0 += 64) {
    __syncthreads();
#pragma unroll
    for (int i = 0; i < 8; ++i) {
      const ushort* g = gsrc + (size_t)(i * 8 + r8) * gs + (k0 + c8 * 8);
      gload16(g, lbase + i * 512);
    }
    __syncthreads();
#pragma unroll
    for (int kk = 0; kk < 2; ++kk) {
      bf16x8 af[4], bfr[4];
#pragma unroll
      for (int i = 0; i < 4; ++i)
        af[i] = *(const bf16x8*)(As + (wm + i * 16 + lr) * 64 +
                                 (kk * 4 + kq) * 8);
#pragma unroll
      for (int j = 0; j < 4; ++j)
        bfr[j] = *(const bf16x8*)(Bs + (wn + j * 16 + lr) * 64 +
                                  (kk * 4 + kq) * 8);
#pragma unroll
      for (int i = 0; i < 4; ++i)
#pragma unroll
        for (int j = 0; j < 4; ++j)
          acc[i][j] = __builtin_amdgcn_mfma_f32_16x16x32_bf16(
              af[i], bfr[j], acc[i][j], 0, 0, 0);
    }
  }

#pragma unroll
  for (int i = 0; i < 4; ++i) {
#pragma unroll
    for (int j = 0; j < 4; ++j) {
#pragma unroll
      for (int t = 0; t < 4; ++t) {
        const int mr = m0 + wm + i * 16 + kq * 4 + t;
        const int nc = n0 + wn + j * 16 + lr;
        const float val = acc[i][j][t];
        if constexpr (MODE == G_EMBED) {
          aux[(size_t)mr * 512 + nc] = f2bf(val);
        } else if constexpr (MODE == G_QKV) {
          const int sect = nc >> 9;       // 0=q 1=k 2=v
          const int c = nc & 511;
          const int br = c >> 8;
          const int hd = (c >> 5) & 7;
          const int d = c & 31;
          const int bb = mr >> 12;
          const int l = mr & 4095;
          const int win = br ? (l >> 9) : ((l >> 3) & 7);
          const int pp = br ? (l & 511) : (((l >> 6) << 3) | (l & 7));
          const size_t off =
              (((((size_t)br * 4 + bb) * 8 + win) * 8 + hd) * 512 + pp) * 32 +
              d;
          if (sect == 0) {
            aux[off] = f2bf(val * kExpC);  // aux = qp
          } else if (sect == 1) {
            kp[off] = f2bf(val);
          } else {
            const ushort bv = f2bf(val);
            vp[off] = bv;
            vrow[(size_t)mr * 512 + c] = bv;
          }
        } else {  // G_PROJ
          const float v2 =
              val + bf2f(resid[(size_t)mr * 512 + nc]) + bias[nc];
          aux[(size_t)mr * 512 + nc] = f2bf(v2);
        }
      }
    }
  }
}

// ---------------------------------------------------------------------------
// Merged OUT+VOUT GEMM (one dispatch, grid 512) with the same XCD remap:
// blocks' widx [0,256) -> out = w_out^T @ xo^T, [256,512) -> vout (v).
// ---------------------------------------------------------------------------
__global__ __launch_bounds__(256) void gemm_out2(
    const ushort* __restrict__ A, const ushort* __restrict__ Bt0,
    const ushort* __restrict__ Bt1, float* __restrict__ C) {
  constexpr int KD = 512;
  constexpr int NT = Mtot / 128;  // 128
  __shared__ ushort As[128 * 64];
  __shared__ ushort Bs[128 * 64];

  const int widx = (blockIdx.x & 7) * 64 + (blockIdx.x >> 3);
  const int sel = widx >> 8;
  const int bid = widx & 255;
  const ushort* Bt = sel ? Bt1 : Bt0;
  const size_t outBase = sel ? (size_t)Bn * DIMn * Ln : 0;

  const int tid = threadIdx.x;
  const int wid = tid >> 6;
  const int lane = tid & 63;
  const int m0 = (bid / NT) * 128;
  const int n0 = (bid % NT) * 128;

  const ushort* gsrc = (wid < 2)
                           ? A + (size_t)(m0 + (wid & 1) * 64) * KD
                           : Bt + (size_t)(n0 + (wid & 1) * 64) * KD;
  ushort* lbase = (wid < 2 ? As : Bs) + (wid & 1) * (64 * 64);
  const int r8 = lane >> 3;
  const int c8 = lane & 7;

  f32x4 acc[4][4];
#pragma unroll
  for (int i = 0; i < 4; ++i)
#pragma unroll
    for (int j = 0; j < 4; ++j) acc[i][j] = (f32x4){0.f, 0.f, 0.f, 0.f};

  const int wm = (wid & 1) * 64;
  const int wn = (wid >> 1) * 64;
  const int lr = lane & 15;
  const int kq = lane >> 4;

  for (int k0 = 0; k0 < KD; k0 += 64) {
    __syncthreads();
#pragma unroll
    for (int i = 0; i < 8; ++i) {
      const ushort* g = gsrc + (size_t)(i * 8 + r8) * KD + (k0 + c8 * 8);
      gload16(g, lbase + i * 512);
    }
    __syncthreads();
#pragma unroll
    for (int kk = 0; kk < 2; ++kk) {
      bf16x8 af[4], bfr[4];
#pragma unroll
      for (int i = 0; i < 4; ++i)
        af[i] = *(const bf16x8*)(As + (wm + i * 16 + lr) * 64 +
                                 (kk * 4 + kq) * 8);
#pragma unroll
      for (int j = 0; j < 4; ++j)
        bfr[j] = *(const bf16x8*)(Bs + (wn + j * 16 + lr) * 64 +
                                  (kk * 4 + kq) * 8);
#pragma unroll
      for (int i = 0; i < 4; ++i)
#pragma unroll
        for (int j = 0; j < 4; ++j)
          acc[i][j] = __builtin_amdgcn_mfma_f32_16x16x32_bf16(
              af[i], bfr[j], acc[i][j], 0, 0, 0);
    }
  }

#pragma unroll
  for (int i = 0; i < 4; ++i)
#pragma unroll
    for (int j = 0; j < 4; ++j)
#pragma unroll
      for (int t = 0; t < 4; ++t) {
        const int mr = m0 + wm + i * 16 + kq * 4 + t;  // channel
        const int nc = n0 + wn + j * 16 + lr;          // token
        C[outBase + ((size_t)(nc >> 12)) * ((size_t)DIMn * Ln) +
          (size_t)mr * Ln + (nc & 4095)] = acc[i][j][t];
      }
}

// ---------------------------------------------------------------------------
// Merged conversions, one dispatch (grid 1344):
//  blocks [0,320): weight transposes (f32 [K][N] -> bf16 [N][K], 64x64 tiles)
//  blocks [320,1344): x [B][256][4096] f32 -> xe [B*4096][256] bf16
// ---------------------------------------------------------------------------
__global__ __launch_bounds__(256) void cvt_all(
    const float* __restrict__ w_embed, const float* __restrict__ w_qkv,
    const float* __restrict__ w_proj, const float* __restrict__ w_out,
    const float* __restrict__ x, ushort* __restrict__ we_t,
    ushort* __restrict__ wq_t, ushort* __restrict__ wp_t,
    ushort* __restrict__ wo_t, ushort* __restrict__ xe) {
  __shared__ ushort tile[64][65];
  const int blk0 = blockIdx.x;
  if (blk0 < 320) {
    const int blk = blk0;
    const float* in;
    ushort* out;
    int K, N, ti;
    if (blk < 32) {
      in = w_embed; out = we_t; K = 256; N = 512; ti = blk;
    } else if (blk < 224) {
      in = w_qkv; out = wq_t; K = 512; N = 1536; ti = blk - 32;
    } else if (blk < 288) {
      in = w_proj; out = wp_t; K = 512; N = 512; ti = blk - 224;
    } else {
      in = w_out; out = wo_t; K = 512; N = 256; ti = blk - 288;
    }
    const int ntN = N >> 6;
    const int k0 = (ti / ntN) << 6;
    const int n0 = (ti % ntN) << 6;
    const int c = threadIdx.x & 63;
    const int g = threadIdx.x >> 6;
#pragma unroll
    for (int it = 0; it < 16; ++it) {
      const int r = it * 4 + g;
      tile[r][c] = f2bf(in[(size_t)(k0 + r) * N + n0 + c]);
    }
    __syncthreads();
#pragma unroll
    for (int it = 0; it < 16; ++it) {
      const int nn = it * 4 + g;
      out[(size_t)(n0 + nn) * K + k0 + c] = tile[c][nn];
    }
  } else {
    const int blk = blk0 - 320;
    const int lt = blk & 63;
    const int ct = (blk >> 6) & 3;
    const int b = blk >> 8;
    const int l0 = lt * 64, c0 = ct * 64;
    const int t = threadIdx.x;
    const int lanel = t & 63;
    const int grp = t >> 6;
#pragma unroll
    for (int it = 0; it < 16; ++it) {
      const int c = grp * 16 + it;
      tile[c][lanel] = f2bf(
          x[(size_t)b * (DIMn * Ln) + (size_t)(c0 + c) * Ln + l0 + lanel]);
    }
    __syncthreads();
#pragma unroll
    for (int it = 0; it < 16; ++it) {
      const int l = grp * 16 + it;
      xe[((size_t)b * Ln + l0 + l) * 256 + c0 + lanel] = tile[lanel][l];
    }
  }
}

__global__ __launch_bounds__(128) void ln_fuse(const ushort* __restrict__ x2,
                                               const float* __restrict__ g1,
                                               const float* __restrict__ b1,
                                               ushort* __restrict__ xln) {
  const int row = blockIdx.x;
  const int t = threadIdx.x;
  const ushort4 u4 = *(const ushort4*)&x2[(size_t)row * 512 + t * 4];
  float v[4] = {bf2f(u4.x), bf2f(u4.y), bf2f(u4.z), bf2f(u4.w)};
  float s = v[0] + v[1] + v[2] + v[3];
  float s2 = v[0] * v[0] + v[1] * v[1] + v[2] * v[2] + v[3] * v[3];
#pragma unroll
  for (int off = 32; off > 0; off >>= 1) {
    s += __shfl_down(s, off);
    s2 += __shfl_down(s2, off);
  }
  __shared__ float red[4];
  if ((t & 63) == 0) {
    red[t >> 6] = s;
    red[2 + (t >> 6)] = s2;
  }
  __syncthreads();
  const float S = red[0] + red[1];
  const float S2 = red[2] + red[3];
  const float mu = S * (1.f / 512.f);
  const float rs = rsqrtf(S2 * (1.f / 512.f) - mu * mu + kEps);
  const float4 g = *(const float4*)&g1[t * 4];
  const float4 bb = *(const float4*)&b1[t * 4];
  ushort4 o;
  o.x = f2bf((v[0] - mu) * rs * g.x + bb.x);
  o.y = f2bf((v[1] - mu) * rs * g.y + bb.y);
  o.z = f2bf((v[2] - mu) * rs * g.z + bb.z);
  o.w = f2bf((v[3] - mu) * rs * g.w + bb.w);
  *(ushort4*)&xln[(size_t)row * 512 + t * 4] = o;
}

// ---------------------------------------------------------------------------
// MFMA attention + LePE — R12-EXACT (HW-proven; sync schedule FROZEN:
// R13/R14/R17 kt-loop edits all NaN'd). Permuted q/k/v, XCD-paired
// qh-halves, 2 barriers/iter, in-loop K staging, lane-local softmax.
// ---------------------------------------------------------------------------
__global__ __launch_bounds__(256, 4) void attn_m(
    const ushort* __restrict__ qp, const ushort* __restrict__ kp,
    const ushort* __restrict__ vp, ushort* __restrict__ obf,
    const float* __restrict__ cw0, const float* __restrict__ cb0,
    const float* __restrict__ cw1, const float* __restrict__ cb1) {
  __shared__ ushort VtS[32 * 520];  // Vt[d][token]
  __shared__ ushort KsS[32 * 40];   // permuted key tiles
  __shared__ float denS[4 * 64];
  __shared__ float cwS[288];
  __shared__ float cbS[32];

  // XCD pairing: qh-pair (work 2k,2k+1) <-> blockIdx 8 apart -> same XCD
  const int work = ((blockIdx.x & 7) << 7) | (blockIdx.x >> 3);
  const int branch = work >> 9;
  const int b = (work >> 7) & 3;
  const int win = (work >> 4) & 7;
  const int head = (work >> 1) & 7;
  const int qh = work & 1;
  const int tid = threadIdx.x;
  const int w = tid >> 6;
  const int lane = tid & 63;
  const int lr = lane & 15;
  const int kq = lane >> 4;
  const int qcol = branch * CBn + head * HDn;

  const float* cw = branch ? cw1 : cw0;
  const float* cb = branch ? cb1 : cb0;
  for (int i = tid; i < 288; i += 256) cwS[i] = cw[head * 288 + i];
  if (tid < 32) cbS[tid] = cb[head * 32 + tid];

  auto tok2l = [&](int p) -> int {
    return branch == 0 ? ((p >> 3) * 64 + win * 8 + (p & 7)) : (win * 512 + p);
  };
  // base of this (branch,b,win,head) slab in the permuted layout
  const size_t base =
      (((((size_t)branch * 4 + b) * 8 + win) * 8 + head) * 512) * 32;

  // ---- stage Vt[d][p]: 64B/thread, fully sequential ----
#pragma unroll
  for (int rr = 0; rr < 2; ++rr) {
    const int j = tid + rr * 256;
    const ushort* vrow = vp + base + (size_t)j * 32;
#pragma unroll
    for (int g = 0; g < 4; ++g) {
      const bf16x8 u = *(const bf16x8*)(vrow + g * 8);
#pragma unroll
      for (int e = 0; e < 8; ++e)
        VtS[(g * 8 + e) * 520 + j] = (ushort)u[e];
    }
  }

  // ---- preload Q B-frags (pre-scaled by kExpC in QKV epilogue) ----
  bf16x8 qf[4];
#pragma unroll
  for (int qt = 0; qt < 4; ++qt) {
    const int p = qh * 256 + w * 64 + qt * 16 + lr;
    qf[qt] = *(const bf16x8*)(qp + base + (size_t)p * 32 + kq * 8);
  }

  f32x4 acc[4][2];
#pragma unroll
  for (int qt = 0; qt < 4; ++qt) {
    acc[qt][0] = (f32x4){0.f, 0.f, 0.f, 0.f};
    acc[qt][1] = (f32x4){0.f, 0.f, 0.f, 0.f};
  }
  float den[4] = {};
  const f32x4 zero4 = (f32x4){0.f, 0.f, 0.f, 0.f};

  for (int kt = 0; kt < 16; ++kt) {
    const int k0 = kt * 32;
    __syncthreads();
    // stage K tile, PERMUTED rows: key j -> row ((j>>2)&1)*16+(j>>3)*4+(j&3)
    {
      const int j = tid >> 3;
      const int d0 = (tid & 7) * 4;
      const int row = ((j >> 2) & 1) * 16 + (j >> 3) * 4 + (j & 3);
      const ushort4 k4 =
          *(const ushort4*)(kp + base + (size_t)(k0 + j) * 32 + d0);
      *(ushort4*)&KsS[row * 40 + d0] = k4;
    }
    __syncthreads();

    const bf16x8 kf0 = *(const bf16x8*)&KsS[lr * 40 + kq * 8];
    const bf16x8 kf1 = *(const bf16x8*)&KsS[(16 + lr) * 40 + kq * 8];
    const bf16x8 vf0 = *(const bf16x8*)&VtS[lr * 520 + k0 + kq * 8];
    const bf16x8 vf1 = *(const bf16x8*)&VtS[(16 + lr) * 520 + k0 + kq * 8];

#pragma unroll
    for (int qt = 0; qt < 4; ++qt) {
      // swapped: S[q=lr][key] lands in-lane
      const f32x4 s0 =
          __builtin_amdgcn_mfma_f32_16x16x32_bf16(kf0, qf[qt], zero4, 0, 0, 0);
      const f32x4 s1 =
          __builtin_amdgcn_mfma_f32_16x16x32_bf16(kf1, qf[qt], zero4, 0, 0, 0);
      float e0[4], e1[4];
#pragma unroll
      for (int t = 0; t < 4; ++t) {
        e0[t] = __builtin_amdgcn_exp2f(s0[t]);
        e1[t] = __builtin_amdgcn_exp2f(s1[t]);
      }
      den[qt] += (e0[0] + e0[1] + e0[2] + e0[3]) +
                 (e1[0] + e1[1] + e1[2] + e1[3]);
      union {
        unsigned u[4];
        bf16x8 v;
      } pa;
      pa.u[0] = cvtpk(e0[0], e0[1]);
      pa.u[1] = cvtpk(e0[2], e0[3]);
      pa.u[2] = cvtpk(e1[0], e1[1]);
      pa.u[3] = cvtpk(e1[2], e1[3]);
      acc[qt][0] = __builtin_amdgcn_mfma_f32_16x16x32_bf16(pa.v, vf0,
                                                           acc[qt][0], 0, 0, 0);
      acc[qt][1] = __builtin_amdgcn_mfma_f32_16x16x32_bf16(pa.v, vf1,
                                                           acc[qt][1], 0, 0, 0);
    }
  }

  // ---- den: reduce across kq lanes, bounce through per-wave LDS ----
#pragma unroll
  for (int qt = 0; qt < 4; ++qt) {
    float d = den[qt];
    d += __shfl_xor(d, 16);
    d += __shfl_xor(d, 32);
    if (lane < 16) denS[w * 64 + qt * 16 + lr] = d;
  }
  __syncthreads();

  // ---- epilogue: O = PV/den + LePE(Vt), write bf16 ----
  const int Hs = branch ? 8 : 64;
  const int Ws = branch ? 64 : 8;
#pragma unroll
  for (int qt = 0; qt < 4; ++qt) {
#pragma unroll
    for (int t = 0; t < 4; ++t) {
      const int p = qh * 256 + w * 64 + qt * 16 + kq * 4 + t;
      const int l = tok2l(p);
      const int hl = branch ? (p >> 6) : (p >> 3);
      const int wl = branch ? (p & 63) : (p & 7);
      const float inv = 1.f / denS[w * 64 + qt * 16 + kq * 4 + t];
      ushort* orow = obf + ((size_t)b * Ln + l) * 512 + qcol;
#pragma unroll
      for (int dt = 0; dt < 2; ++dt) {
        const int d = dt * 16 + lr;
        float le = cbS[d];
#pragma unroll
        for (int dh = -1; dh <= 1; ++dh) {
          const int hh = hl + dh;
          if (hh < 0 || hh >= Hs) continue;
#pragma unroll
          for (int dw = -1; dw <= 1; ++dw) {
            const int ww = wl + dw;
            if (ww < 0 || ww >= Ws) continue;
            const int pp = hh * Ws + ww;
            le = fmaf(bf2f(VtS[d * 520 + pp]),
                      cwS[d * 9 + (dh + 1) * 3 + (dw + 1)], le);
          }
        }
        orow[d] = f2bf(fmaf(acc[qt][dt][t], inv, le));
      }
    }
  }
}

// ---------------------------------------------------------------------------
extern "C" void kernel_launch(void* const* d_in, const int* in_sizes, int n_in,
                              void* d_out, int out_size, void* d_ws,
                              size_t ws_size, hipStream_t stream) {
  const float* x = (const float*)d_in[0];
  const float* w_embed = (const float*)d_in[1];
  const float* g1 = (const float*)d_in[2];
  const float* b1 = (const float*)d_in[3];
  const float* w_qkv = (const float*)d_in[4];
  const float* cw0 = (const float*)d_in[5];
  const float* cb0 = (const float*)d_in[6];
  const float* cw1 = (const float*)d_in[7];
  const float* cb1 = (const float*)d_in[8];
  const float* w_proj = (const float*)d_in[9];
  const float* b_proj = (const float*)d_in[10];
  const float* w_out = (const float*)d_in[11];
  float* out = (float*)d_out;

  // carve: x2 16.8 | qp 16.8 | kp 16.8 | vp 16.8 | vrow 16.8 | obf 16.8 |
  //        xln/xobf 16.8 | xe 8.4 | weights 2.6  => ~129 MB (< proven 134)
  char* p = (char*)d_ws;
  ushort* x2bf = (ushort*)p;
  p += (size_t)Mtot * 512 * 2;
  ushort* qp = (ushort*)p;
  p += (size_t)Mtot * 512 * 2;
  ushort* kp = (ushort*)p;
  p += (size_t)Mtot * 512 * 2;
  ushort* vp = (ushort*)p;
  p += (size_t)Mtot * 512 * 2;
  ushort* vrow = (ushort*)p;
  p += (size_t)Mtot * 512 * 2;
  ushort* obf = (ushort*)p;
  p += (size_t)Mtot * 512 * 2;
  ushort* xln = (ushort*)p;  // later reused as xobf
  ushort* xobf = (ushort*)p;
  p += (size_t)Mtot * 512 * 2;
  ushort* xe = (ushort*)p;
  p += (size_t)Mtot * 256 * 2;
  ushort* we_t = (ushort*)p;
  p += (size_t)512 * 256 * 2;
  ushort* wq_t = (ushort*)p;
  p += (size_t)1536 * 512 * 2;
  ushort* wp_t = (ushort*)p;
  p += (size_t)512 * 512 * 2;
  ushort* wo_t = (ushort*)p;

  // merged conversions: 320 weight-tiles + 1024 x-tiles in one dispatch
  cvt_all<<<dim3(1344), 256, 0, stream>>>(w_embed, w_qkv, w_proj, w_out, x,
                                          we_t, wq_t, wp_t, wo_t, xe);

  gemm_bf<G_EMBED, 512, 256, 256><<<dim3(128 * 4), 256, 0, stream>>>(
      xe, we_t, nullptr, nullptr, x2bf, nullptr, nullptr, nullptr);
  ln_fuse<<<dim3(Mtot), 128, 0, stream>>>(x2bf, g1, b1, xln);
  gemm_bf<G_QKV, 1536, 512, 512><<<dim3(128 * 12), 256, 0, stream>>>(
      xln, wq_t, nullptr, nullptr, qp, kp, vp, vrow);
  attn_m<<<dim3(1024), 256, 0, stream>>>(qp, kp, vp, obf, cw0, cb0, cw1, cb1);
  gemm_bf<G_PROJ, 512, 512, 512><<<dim3(128 * 4), 256, 0, stream>>>(
      obf, wp_t, x2bf, b_proj, xobf, nullptr, nullptr, nullptr);
  // merged out+vout with XCD remap inside
  gemm_out2<<<dim3(512), 256, 0, stream>>>(wo_t, xobf, vrow, out);
}

// Round 20
// 158.841 us; speedup vs baseline: 1.0698x; 1.0176x over previous
//
#include <hip/hip_runtime.h>
#include <cstdint>

#define Bn 4
#define DIMn 256
#define Ln 4096
#define C2n 512
#define CBn 256
#define HDn 32
#define Mtot (Bn * Ln)

using bf16x8 = __attribute__((ext_vector_type(8))) short;
using us8 = __attribute__((ext_vector_type(8))) ushort;
using f32x4 = __attribute__((ext_vector_type(4))) float;

static constexpr float kScale = 0.17677669529663687f;  // 32^-0.5
static constexpr float kEps = 1e-5f;
static constexpr float kExpC = 0.17677669529663687f * 1.4426950408889634f;

__device__ __forceinline__ ushort f2bf(float f) {
  union {
    float f;
    unsigned u;
  } v;
  v.f = f;
  unsigned r = v.u + 0x7FFFu + ((v.u >> 16) & 1u);
  return (ushort)(r >> 16);
}

__device__ __forceinline__ float bf2f(ushort u) {
  union {
    unsigned u;
    float f;
  } v;
  v.u = (unsigned)u << 16;
  return v.f;
}

// packed 2xf32 -> 2xbf16 (RNE), src0 -> low half [T12 primitive]
__device__ __forceinline__ unsigned cvtpk(float lo, float hi) {
  unsigned r;
  asm("v_cvt_pk_bf16_f32 %0, %1, %2" : "=v"(r) : "v"(lo), "v"(hi));
  return r;
}

__device__ __forceinline__ void gload16(const void* g, void* l) {
  __builtin_amdgcn_global_load_lds(
      (const __attribute__((address_space(1))) unsigned*)g,
      (__attribute__((address_space(3))) unsigned*)l, 16, 0, 0);
}

// ---------------------------------------------------------------------------
// bf16 MFMA GEMM, m97 structure (HW-verified R4/R5): 128x128 tile, BK=64,
// 4 waves 2x2 of 64x64, 16x16x32 MFMA, linear LDS, gload16 staging.
// XCD-aware bijective block remap (T1, verified R16): each XCD gets nwg/8
// CONSECUTIVE work items so all N-blocks sharing an A-panel run on one XCD.
// G_QKV epilogue scatters q/k/v into the attention-permuted layout and
// echoes v row-major; q pre-scaled by kExpC. (Scalar stores kept: R18's
// LDS-bounce wide-store variant measured SLOWER — permuted 2B stores
// already coalesce in 32B sectors.)
// ---------------------------------------------------------------------------
enum { G_EMBED = 0, G_QKV = 1, G_PROJ = 2 };

template <int MODE, int ND, int KD, int LDB>
__global__ __launch_bounds__(256) void gemm_bf(
    const ushort* __restrict__ A, const ushort* __restrict__ Bt,
    const ushort* __restrict__ resid, const float* __restrict__ bias,
    ushort* __restrict__ aux, ushort* __restrict__ kp,
    ushort* __restrict__ vp, ushort* __restrict__ vrow) {
  constexpr int NT = ND / 128;
  __shared__ ushort As[128 * 64];
  __shared__ ushort Bs[128 * 64];

  const int tid = threadIdx.x;
  const int wid = tid >> 6;
  const int lane = tid & 63;
  // XCD remap: blk -> widx so same-A-panel blocks are consecutive per XCD
  const int per = (int)gridDim.x >> 3;
  const int widx = (blockIdx.x & 7) * per + (blockIdx.x >> 3);
  const int m0 = (widx / NT) * 128;
  const int n0 = (widx % NT) * 128;

  const int gs = (wid < 2) ? KD : LDB;
  const ushort* gsrc = (wid < 2)
                           ? A + (size_t)(m0 + (wid & 1) * 64) * KD
                           : Bt + (size_t)(n0 + (wid & 1) * 64) * LDB;
  ushort* lbase = (wid < 2 ? As : Bs) + (wid & 1) * (64 * 64);
  const int r8 = lane >> 3;
  const int c8 = lane & 7;

  f32x4 acc[4][4];
#pragma unroll
  for (int i = 0; i < 4; ++i)
#pragma unroll
    for (int j = 0; j < 4; ++j) acc[i][j] = (f32x4){0.f, 0.f, 0.f, 0.f};

  const int wm = (wid & 1) * 64;
  const int wn = (wid >> 1) * 64;
  const int lr = lane & 15;
  const int kq = lane >> 4;

  for (int k0 = 0; k0 < KD; k0 += 64) {
    __syncthreads();
#pragma unroll
    for (int i = 0; i < 8; ++i) {
      const ushort* g = gsrc + (size_t)(i * 8 + r8) * gs + (k0 + c8 * 8);
      gload16(g, lbase + i * 512);
    }
    __syncthreads();
#pragma unroll
    for (int kk = 0; kk < 2; ++kk) {
      bf16x8 af[4], bfr[4];
#pragma unroll
      for (int i = 0; i < 4; ++i)
        af[i] = *(const bf16x8*)(As + (wm + i * 16 + lr) * 64 +
                                 (kk * 4 + kq) * 8);
#pragma unroll
      for (int j = 0; j < 4; ++j)
        bfr[j] = *(const bf16x8*)(Bs + (wn + j * 16 + lr) * 64 +
                                  (kk * 4 + kq) * 8);
#pragma unroll
      for (int i = 0; i < 4; ++i)
#pragma unroll
        for (int j = 0; j < 4; ++j)
          acc[i][j] = __builtin_amdgcn_mfma_f32_16x16x32_bf16(
              af[i], bfr[j], acc[i][j], 0, 0, 0);
    }
  }

#pragma unroll
  for (int i = 0; i < 4; ++i) {
#pragma unroll
    for (int j = 0; j < 4; ++j) {
#pragma unroll
      for (int t = 0; t < 4; ++t) {
        const int mr = m0 + wm + i * 16 + kq * 4 + t;
        const int nc = n0 + wn + j * 16 + lr;
        const float val = acc[i][j][t];
        if constexpr (MODE == G_EMBED) {
          aux[(size_t)mr * 512 + nc] = f2bf(val);
        } else if constexpr (MODE == G_QKV) {
          const int sect = nc >> 9;       // 0=q 1=k 2=v
          const int c = nc & 511;
          const int br = c >> 8;
          const int hd = (c >> 5) & 7;
          const int d = c & 31;
          const int bb = mr >> 12;
          const int l = mr & 4095;
          const int win = br ? (l >> 9) : ((l >> 3) & 7);
          const int pp = br ? (l & 511) : (((l >> 6) << 3) | (l & 7));
          const size_t off =
              (((((size_t)br * 4 + bb) * 8 + win) * 8 + hd) * 512 + pp) * 32 +
              d;
          if (sect == 0) {
            aux[off] = f2bf(val * kExpC);  // aux = qp
          } else if (sect == 1) {
            kp[off] = f2bf(val);
          } else {
            const ushort bv = f2bf(val);
            vp[off] = bv;
            vrow[(size_t)mr * 512 + c] = bv;
          }
        } else {  // G_PROJ
          const float v2 =
              val + bf2f(resid[(size_t)mr * 512 + nc]) + bias[nc];
          aux[(size_t)mr * 512 + nc] = f2bf(v2);
        }
      }
    }
  }
}

// ---------------------------------------------------------------------------
// Merged OUT+VOUT GEMM (one dispatch, grid 512) with the same XCD remap:
// blocks' widx [0,256) -> out = w_out^T @ xo^T, [256,512) -> vout (v).
// ---------------------------------------------------------------------------
__global__ __launch_bounds__(256) void gemm_out2(
    const ushort* __restrict__ A, const ushort* __restrict__ Bt0,
    const ushort* __restrict__ Bt1, float* __restrict__ C) {
  constexpr int KD = 512;
  constexpr int NT = Mtot / 128;  // 128
  __shared__ ushort As[128 * 64];
  __shared__ ushort Bs[128 * 64];

  const int widx = (blockIdx.x & 7) * 64 + (blockIdx.x >> 3);
  const int sel = widx >> 8;
  const int bid = widx & 255;
  const ushort* Bt = sel ? Bt1 : Bt0;
  const size_t outBase = sel ? (size_t)Bn * DIMn * Ln : 0;

  const int tid = threadIdx.x;
  const int wid = tid >> 6;
  const int lane = tid & 63;
  const int m0 = (bid / NT) * 128;
  const int n0 = (bid % NT) * 128;

  const ushort* gsrc = (wid < 2)
                           ? A + (size_t)(m0 + (wid & 1) * 64) * KD
                           : Bt + (size_t)(n0 + (wid & 1) * 64) * KD;
  ushort* lbase = (wid < 2 ? As : Bs) + (wid & 1) * (64 * 64);
  const int r8 = lane >> 3;
  const int c8 = lane & 7;

  f32x4 acc[4][4];
#pragma unroll
  for (int i = 0; i < 4; ++i)
#pragma unroll
    for (int j = 0; j < 4; ++j) acc[i][j] = (f32x4){0.f, 0.f, 0.f, 0.f};

  const int wm = (wid & 1) * 64;
  const int wn = (wid >> 1) * 64;
  const int lr = lane & 15;
  const int kq = lane >> 4;

  for (int k0 = 0; k0 < KD; k0 += 64) {
    __syncthreads();
#pragma unroll
    for (int i = 0; i < 8; ++i) {
      const ushort* g = gsrc + (size_t)(i * 8 + r8) * KD + (k0 + c8 * 8);
      gload16(g, lbase + i * 512);
    }
    __syncthreads();
#pragma unroll
    for (int kk = 0; kk < 2; ++kk) {
      bf16x8 af[4], bfr[4];
#pragma unroll
      for (int i = 0; i < 4; ++i)
        af[i] = *(const bf16x8*)(As + (wm + i * 16 + lr) * 64 +
                                 (kk * 4 + kq) * 8);
#pragma unroll
      for (int j = 0; j < 4; ++j)
        bfr[j] = *(const bf16x8*)(Bs + (wn + j * 16 + lr) * 64 +
                                  (kk * 4 + kq) * 8);
#pragma unroll
      for (int i = 0; i < 4; ++i)
#pragma unroll
        for (int j = 0; j < 4; ++j)
          acc[i][j] = __builtin_amdgcn_mfma_f32_16x16x32_bf16(
              af[i], bfr[j], acc[i][j], 0, 0, 0);
    }
  }

#pragma unroll
  for (int i = 0; i < 4; ++i)
#pragma unroll
    for (int j = 0; j < 4; ++j)
#pragma unroll
      for (int t = 0; t < 4; ++t) {
        const int mr = m0 + wm + i * 16 + kq * 4 + t;  // channel
        const int nc = n0 + wn + j * 16 + lr;          // token
        C[outBase + ((size_t)(nc >> 12)) * ((size_t)DIMn * Ln) +
          (size_t)mr * Ln + (nc & 4095)] = acc[i][j][t];
      }
}

// ---------------------------------------------------------------------------
// Merged conversions, one dispatch (grid 1344):
//  blocks [0,320): weight transposes (f32 [K][N] -> bf16 [N][K], 64x64 tiles)
//  blocks [320,1344): x [B][256][4096] f32 -> xe [B*4096][256] bf16
// ---------------------------------------------------------------------------
__global__ __launch_bounds__(256) void cvt_all(
    const float* __restrict__ w_embed, const float* __restrict__ w_qkv,
    const float* __restrict__ w_proj, const float* __restrict__ w_out,
    const float* __restrict__ x, ushort* __restrict__ we_t,
    ushort* __restrict__ wq_t, ushort* __restrict__ wp_t,
    ushort* __restrict__ wo_t, ushort* __restrict__ xe) {
  __shared__ ushort tile[64][65];
  const int blk0 = blockIdx.x;
  if (blk0 < 320) {
    const int blk = blk0;
    const float* in;
    ushort* out;
    int K, N, ti;
    if (blk < 32) {
      in = w_embed; out = we_t; K = 256; N = 512; ti = blk;
    } else if (blk < 224) {
      in = w_qkv; out = wq_t; K = 512; N = 1536; ti = blk - 32;
    } else if (blk < 288) {
      in = w_proj; out = wp_t; K = 512; N = 512; ti = blk - 224;
    } else {
      in = w_out; out = wo_t; K = 512; N = 256; ti = blk - 288;
    }
    const int ntN = N >> 6;
    const int k0 = (ti / ntN) << 6;
    const int n0 = (ti % ntN) << 6;
    const int c = threadIdx.x & 63;
    const int g = threadIdx.x >> 6;
#pragma unroll
    for (int it = 0; it < 16; ++it) {
      const int r = it * 4 + g;
      tile[r][c] = f2bf(in[(size_t)(k0 + r) * N + n0 + c]);
    }
    __syncthreads();
#pragma unroll
    for (int it = 0; it < 16; ++it) {
      const int nn = it * 4 + g;
      out[(size_t)(n0 + nn) * K + k0 + c] = tile[c][nn];
    }
  } else {
    const int blk = blk0 - 320;
    const int lt = blk & 63;
    const int ct = (blk >> 6) & 3;
    const int b = blk >> 8;
    const int l0 = lt * 64, c0 = ct * 64;
    const int t = threadIdx.x;
    const int lanel = t & 63;
    const int grp = t >> 6;
#pragma unroll
    for (int it = 0; it < 16; ++it) {
      const int c = grp * 16 + it;
      tile[c][lanel] = f2bf(
          x[(size_t)b * (DIMn * Ln) + (size_t)(c0 + c) * Ln + l0 + lanel]);
    }
    __syncthreads();
#pragma unroll
    for (int it = 0; it < 16; ++it) {
      const int l = grp * 16 + it;
      xe[((size_t)b * Ln + l0 + l) * 256 + c0 + lanel] = tile[lanel][l];
    }
  }
}

// ---------------------------------------------------------------------------
// LayerNorm, one WAVE per row (R20): 4096 blocks x 256 thr = 4 rows/block,
// 64 lanes/row, ushort8 loads, pure shfl reduction + lane-0 broadcast.
// Zero LDS, zero barriers (replaces the 128-thr LDS-bounce version).
// ---------------------------------------------------------------------------
__global__ __launch_bounds__(256) void ln_fuse(const ushort* __restrict__ x2,
                                               const float* __restrict__ g1,
                                               const float* __restrict__ b1,
                                               ushort* __restrict__ xln) {
  const int row = blockIdx.x * 4 + (threadIdx.x >> 6);
  const int lane = threadIdx.x & 63;
  const us8 u = *(const us8*)&x2[(size_t)row * 512 + lane * 8];
  float v[8];
  float s = 0.f, s2 = 0.f;
#pragma unroll
  for (int e = 0; e < 8; ++e) {
    v[e] = bf2f(u[e]);
    s += v[e];
    s2 += v[e] * v[e];
  }
#pragma unroll
  for (int off = 32; off > 0; off >>= 1) {
    s += __shfl_down(s, off);
    s2 += __shfl_down(s2, off);
  }
  s = __shfl(s, 0);
  s2 = __shfl(s2, 0);
  const float mu = s * (1.f / 512.f);
  const float rs = rsqrtf(s2 * (1.f / 512.f) - mu * mu + kEps);
  const float4 ga = *(const float4*)&g1[lane * 8];
  const float4 gb = *(const float4*)&g1[lane * 8 + 4];
  const float4 ba = *(const float4*)&b1[lane * 8];
  const float4 bb = *(const float4*)&b1[lane * 8 + 4];
  const float gv[8] = {ga.x, ga.y, ga.z, ga.w, gb.x, gb.y, gb.z, gb.w};
  const float bv[8] = {ba.x, ba.y, ba.z, ba.w, bb.x, bb.y, bb.z, bb.w};
  us8 o;
#pragma unroll
  for (int e = 0; e < 8; ++e)
    o[e] = f2bf((v[e] - mu) * rs * gv[e] + bv[e]);
  *(us8*)&xln[(size_t)row * 512 + lane * 8] = o;
}

// ---------------------------------------------------------------------------
// MFMA attention + LePE — R12-EXACT (HW-proven; sync schedule FROZEN:
// R13/R14/R17 kt-loop edits all NaN'd). Permuted q/k/v, XCD-paired
// qh-halves, 2 barriers/iter, in-loop K staging, lane-local softmax.
// ---------------------------------------------------------------------------
__global__ __launch_bounds__(256, 4) void attn_m(
    const ushort* __restrict__ qp, const ushort* __restrict__ kp,
    const ushort* __restrict__ vp, ushort* __restrict__ obf,
    const float* __restrict__ cw0, const float* __restrict__ cb0,
    const float* __restrict__ cw1, const float* __restrict__ cb1) {
  __shared__ ushort VtS[32 * 520];  // Vt[d][token]
  __shared__ ushort KsS[32 * 40];   // permuted key tiles
  __shared__ float denS[4 * 64];
  __shared__ float cwS[288];
  __shared__ float cbS[32];

  // XCD pairing: qh-pair (work 2k,2k+1) <-> blockIdx 8 apart -> same XCD
  const int work = ((blockIdx.x & 7) << 7) | (blockIdx.x >> 3);
  const int branch = work >> 9;
  const int b = (work >> 7) & 3;
  const int win = (work >> 4) & 7;
  const int head = (work >> 1) & 7;
  const int qh = work & 1;
  const int tid = threadIdx.x;
  const int w = tid >> 6;
  const int lane = tid & 63;
  const int lr = lane & 15;
  const int kq = lane >> 4;
  const int qcol = branch * CBn + head * HDn;

  const float* cw = branch ? cw1 : cw0;
  const float* cb = branch ? cb1 : cb0;
  for (int i = tid; i < 288; i += 256) cwS[i] = cw[head * 288 + i];
  if (tid < 32) cbS[tid] = cb[head * 32 + tid];

  auto tok2l = [&](int p) -> int {
    return branch == 0 ? ((p >> 3) * 64 + win * 8 + (p & 7)) : (win * 512 + p);
  };
  // base of this (branch,b,win,head) slab in the permuted layout
  const size_t base =
      (((((size_t)branch * 4 + b) * 8 + win) * 8 + head) * 512) * 32;

  // ---- stage Vt[d][p]: 64B/thread, fully sequential ----
#pragma unroll
  for (int rr = 0; rr < 2; ++rr) {
    const int j = tid + rr * 256;
    const ushort* vrow = vp + base + (size_t)j * 32;
#pragma unroll
    for (int g = 0; g < 4; ++g) {
      const bf16x8 u = *(const bf16x8*)(vrow + g * 8);
#pragma unroll
      for (int e = 0; e < 8; ++e)
        VtS[(g * 8 + e) * 520 + j] = (ushort)u[e];
    }
  }

  // ---- preload Q B-frags (pre-scaled by kExpC in QKV epilogue) ----
  bf16x8 qf[4];
#pragma unroll
  for (int qt = 0; qt < 4; ++qt) {
    const int p = qh * 256 + w * 64 + qt * 16 + lr;
    qf[qt] = *(const bf16x8*)(qp + base + (size_t)p * 32 + kq * 8);
  }

  f32x4 acc[4][2];
#pragma unroll
  for (int qt = 0; qt < 4; ++qt) {
    acc[qt][0] = (f32x4){0.f, 0.f, 0.f, 0.f};
    acc[qt][1] = (f32x4){0.f, 0.f, 0.f, 0.f};
  }
  float den[4] = {};
  const f32x4 zero4 = (f32x4){0.f, 0.f, 0.f, 0.f};

  for (int kt = 0; kt < 16; ++kt) {
    const int k0 = kt * 32;
    __syncthreads();
    // stage K tile, PERMUTED rows: key j -> row ((j>>2)&1)*16+(j>>3)*4+(j&3)
    {
      const int j = tid >> 3;
      const int d0 = (tid & 7) * 4;
      const int row = ((j >> 2) & 1) * 16 + (j >> 3) * 4 + (j & 3);
      const ushort4 k4 =
          *(const ushort4*)(kp + base + (size_t)(k0 + j) * 32 + d0);
      *(ushort4*)&KsS[row * 40 + d0] = k4;
    }
    __syncthreads();

    const bf16x8 kf0 = *(const bf16x8*)&KsS[lr * 40 + kq * 8];
    const bf16x8 kf1 = *(const bf16x8*)&KsS[(16 + lr) * 40 + kq * 8];
    const bf16x8 vf0 = *(const bf16x8*)&VtS[lr * 520 + k0 + kq * 8];
    const bf16x8 vf1 = *(const bf16x8*)&VtS[(16 + lr) * 520 + k0 + kq * 8];

#pragma unroll
    for (int qt = 0; qt < 4; ++qt) {
      // swapped: S[q=lr][key] lands in-lane
      const f32x4 s0 =
          __builtin_amdgcn_mfma_f32_16x16x32_bf16(kf0, qf[qt], zero4, 0, 0, 0);
      const f32x4 s1 =
          __builtin_amdgcn_mfma_f32_16x16x32_bf16(kf1, qf[qt], zero4, 0, 0, 0);
      float e0[4], e1[4];
#pragma unroll
      for (int t = 0; t < 4; ++t) {
        e0[t] = __builtin_amdgcn_exp2f(s0[t]);
        e1[t] = __builtin_amdgcn_exp2f(s1[t]);
      }
      den[qt] += (e0[0] + e0[1] + e0[2] + e0[3]) +
                 (e1[0] + e1[1] + e1[2] + e1[3]);
      union {
        unsigned u[4];
        bf16x8 v;
      } pa;
      pa.u[0] = cvtpk(e0[0], e0[1]);
      pa.u[1] = cvtpk(e0[2], e0[3]);
      pa.u[2] = cvtpk(e1[0], e1[1]);
      pa.u[3] = cvtpk(e1[2], e1[3]);
      acc[qt][0] = __builtin_amdgcn_mfma_f32_16x16x32_bf16(pa.v, vf0,
                                                           acc[qt][0], 0, 0, 0);
      acc[qt][1] = __builtin_amdgcn_mfma_f32_16x16x32_bf16(pa.v, vf1,
                                                           acc[qt][1], 0, 0, 0);
    }
  }

  // ---- den: reduce across kq lanes, bounce through per-wave LDS ----
#pragma unroll
  for (int qt = 0; qt < 4; ++qt) {
    float d = den[qt];
    d += __shfl_xor(d, 16);
    d += __shfl_xor(d, 32);
    if (lane < 16) denS[w * 64 + qt * 16 + lr] = d;
  }
  __syncthreads();

  // ---- epilogue: O = PV/den + LePE(Vt), write bf16 ----
  const int Hs = branch ? 8 : 64;
  const int Ws = branch ? 64 : 8;
#pragma unroll
  for (int qt = 0; qt < 4; ++qt) {
#pragma unroll
    for (int t = 0; t < 4; ++t) {
      const int p = qh * 256 + w * 64 + qt * 16 + kq * 4 + t;
      const int l = tok2l(p);
      const int hl = branch ? (p >> 6) : (p >> 3);
      const int wl = branch ? (p & 63) : (p & 7);
      const float inv = 1.f / denS[w * 64 + qt * 16 + kq * 4 + t];
      ushort* orow = obf + ((size_t)b * Ln + l) * 512 + qcol;
#pragma unroll
      for (int dt = 0; dt < 2; ++dt) {
        const int d = dt * 16 + lr;
        float le = cbS[d];
#pragma unroll
        for (int dh = -1; dh <= 1; ++dh) {
          const int hh = hl + dh;
          if (hh < 0 || hh >= Hs) continue;
#pragma unroll
          for (int dw = -1; dw <= 1; ++dw) {
            const int ww = wl + dw;
            if (ww < 0 || ww >= Ws) continue;
            const int pp = hh * Ws + ww;
            le = fmaf(bf2f(VtS[d * 520 + pp]),
                      cwS[d * 9 + (dh + 1) * 3 + (dw + 1)], le);
          }
        }
        orow[d] = f2bf(fmaf(acc[qt][dt][t], inv, le));
      }
    }
  }
}

// ---------------------------------------------------------------------------
extern "C" void kernel_launch(void* const* d_in, const int* in_sizes, int n_in,
                              void* d_out, int out_size, void* d_ws,
                              size_t ws_size, hipStream_t stream) {
  const float* x = (const float*)d_in[0];
  const float* w_embed = (const float*)d_in[1];
  const float* g1 = (const float*)d_in[2];
  const float* b1 = (const float*)d_in[3];
  const float* w_qkv = (const float*)d_in[4];
  const float* cw0 = (const float*)d_in[5];
  const float* cb0 = (const float*)d_in[6];
  const float* cw1 = (const float*)d_in[7];
  const float* cb1 = (const float*)d_in[8];
  const float* w_proj = (const float*)d_in[9];
  const float* b_proj = (const float*)d_in[10];
  const float* w_out = (const float*)d_in[11];
  float* out = (float*)d_out;

  // carve: x2 16.8 | qp 16.8 | kp 16.8 | vp 16.8 | vrow 16.8 | obf 16.8 |
  //        xln/xobf 16.8 | xe 8.4 | weights 2.6  => ~129 MB (< proven 134)
  char* p = (char*)d_ws;
  ushort* x2bf = (ushort*)p;
  p += (size_t)Mtot * 512 * 2;
  ushort* qp = (ushort*)p;
  p += (size_t)Mtot * 512 * 2;
  ushort* kp = (ushort*)p;
  p += (size_t)Mtot * 512 * 2;
  ushort* vp = (ushort*)p;
  p += (size_t)Mtot * 512 * 2;
  ushort* vrow = (ushort*)p;
  p += (size_t)Mtot * 512 * 2;
  ushort* obf = (ushort*)p;
  p += (size_t)Mtot * 512 * 2;
  ushort* xln = (ushort*)p;  // later reused as xobf
  ushort* xobf = (ushort*)p;
  p += (size_t)Mtot * 512 * 2;
  ushort* xe = (ushort*)p;
  p += (size_t)Mtot * 256 * 2;
  ushort* we_t = (ushort*)p;
  p += (size_t)512 * 256 * 2;
  ushort* wq_t = (ushort*)p;
  p += (size_t)1536 * 512 * 2;
  ushort* wp_t = (ushort*)p;
  p += (size_t)512 * 512 * 2;
  ushort* wo_t = (ushort*)p;

  // merged conversions: 320 weight-tiles + 1024 x-tiles in one dispatch
  cvt_all<<<dim3(1344), 256, 0, stream>>>(w_embed, w_qkv, w_proj, w_out, x,
                                          we_t, wq_t, wp_t, wo_t, xe);

  gemm_bf<G_EMBED, 512, 256, 256><<<dim3(128 * 4), 256, 0, stream>>>(
      xe, we_t, nullptr, nullptr, x2bf, nullptr, nullptr, nullptr);
  ln_fuse<<<dim3(Mtot / 4), 256, 0, stream>>>(x2bf, g1, b1, xln);
  gemm_bf<G_QKV, 1536, 512, 512><<<dim3(128 * 12), 256, 0, stream>>>(
      xln, wq_t, nullptr, nullptr, qp, kp, vp, vrow);
  attn_m<<<dim3(1024), 256, 0, stream>>>(qp, kp, vp, obf, cw0, cb0, cw1, cb1);
  gemm_bf<G_PROJ, 512, 512, 512><<<dim3(128 * 4), 256, 0, stream>>>(
      obf, wp_t, x2bf, b_proj, xobf, nullptr, nullptr, nullptr);
  // merged out+vout with XCD remap inside
  gemm_out2<<<dim3(512), 256, 0, stream>>>(wo_t, xobf, vrow, out);
}